// Round 13
// baseline (169.191 us; speedup 1.0000x reference)
//
#include <hip/hip_runtime.h>
#include <hip/hip_bf16.h>
#include <stdint.h>

typedef __bf16 bf16x8 __attribute__((ext_vector_type(8)));
typedef float f32x4 __attribute__((ext_vector_type(4)));

#define MAXD 40
#define ND   81
#define CSZ  256
#define HSZ  128
#define WSZ  416
#define HW   (HSZ * WSZ)

#define ALC  420        // dword row stride: 4-row step 1680 ≡ 16 (mod 32) -> 2-way (free)
#define EL   0          // even buf, L rows 0..15
#define ER   6720       // even buf, R rows
#define OL   13440      // odd buf, L  (also epilogue scratch base)
#define ORR  20160      // odd buf, R
#define ESTR 420        // epilogue row stride

union U8 { uint32_t u[4]; bf16x8 v; };

static __device__ __forceinline__ uint32_t pk2(float a, float b) {
    union { __bf16 h[2]; uint32_t u; } v;
    v.h[0] = (__bf16)a; v.h[1] = (__bf16)b;
    return v.u;
}

// async global->LDS DMA, 16B/lane; LDS dst = wave-uniform base + lane*16
static __device__ __forceinline__ void gl16(const float* g, const float* l) {
    __builtin_amdgcn_global_load_lds(
        (const __attribute__((address_space(1))) void*)(uintptr_t)g,
        (__attribute__((address_space(3))) void*)(uint32_t)(uintptr_t)l,
        16, 0, 0);
}

static __device__ __forceinline__ void full_barrier() {
    asm volatile("s_waitcnt vmcnt(0) lgkmcnt(0)" ::: "memory");
    __builtin_amdgcn_s_barrier();
    __builtin_amdgcn_sched_barrier(0);
}

static __device__ __forceinline__ void lds_barrier() {
    asm volatile("s_waitcnt lgkmcnt(0)" ::: "memory");
    __builtin_amdgcn_s_barrier();
    __builtin_amdgcn_sched_barrier(0);
}

__global__ __launch_bounds__(1024)
void corr_mfma_kernel(const float* __restrict__ left,
                      const float* __restrict__ right,
                      float* __restrict__ out) {
    __shared__ float Sh[26880];   // 107520 B: E{L,R} | O{L,R}, fp32 [c][w]

    const int t   = threadIdx.x;
    const int wv  = t >> 6;      // 0..15
    const int l   = t & 63;
    const int l15 = l & 15;
    const int l4  = l >> 4;      // 0..3
    const int b   = blockIdx.x >> 6;   // grid 256: 4 b x 64 h-pairs
    const int hp  = blockIdx.x & 63;

    // wave owns p-pair {p0, p0+1}
    const int p0 = 2 * wv;
    const bool hasP1 = (wv < 15);
    int cb[2]; bool okb[2];
    #pragma unroll
    for (int pi = 0; pi < 2; ++pi) {
        const int u = 16 * (p0 + pi) - MAXD + l15;
        okb[pi] = ((unsigned)u < (unsigned)WSZ);
        cb[pi]  = okb[pi] ? u : 0;
    }
    const int FB = 1680 * l4;    // (4*l4)*420 — lane's channel-row base

    // wave-uniform LDS staging destinations
    const float* dEL = &Sh[EL  + wv * ALC];
    const float* dER = &Sh[ER  + wv * ALC];
    const float* dOL = &Sh[OL  + wv * ALC];
    const float* dOR = &Sh[ORR + wv * ALC];

    f32x4 acc0[6], acc1[6];
    #pragma unroll
    for (int k = 0; k < 6; ++k) { acc0[k] = (f32x4)0.0f; acc1[k] = (f32x4)0.0f; }

    const size_t slab0 = ((size_t)b * CSZ) * HW + (size_t)(2 * hp) * WSZ;
    const float* gLw = left  + slab0 + (size_t)wv * HW + 4 * l;
    const float* gRw = right + slab0 + (size_t)wv * HW + 4 * l;

    // ---- prologue: stage slab0 chunk0 -> even ----
    gl16(gLw, dEL); gl16(gRw, dER);
    if (l < 40) { gl16(gLw + 256, dEL + 256); gl16(gRw + 256, dER + 256); }
    full_barrier();

    const float scale = 1.0f / 256.0f;

    for (int s = 0; s < 2; ++s) {
        const float* Ls = gLw + (size_t)s * WSZ;   // slab s = (b, 2hp+s)
        const float* Rs = gRw + (size_t)s * WSZ;

        for (int m = 0; m < 8; ++m) {
            // ======== sub-phase A: stage chunk 2m+1 -> odd; LO halves from even ========
            {
                const size_t co = (size_t)(2 * m + 1) * 16 * HW;
                gl16(Ls + co, dOL); gl16(Rs + co, dOR);
                if (l < 40) { gl16(Ls + co + 256, dOL + 256); gl16(Rs + co + 256, dOR + 256); }
            }
            uint2 aLo[7], bLo[2];
            #pragma unroll
            for (int pi = 0; pi < 2; ++pi) {
                if (pi == 0 || hasP1) {
                    float v0 = Sh[ER + FB +    0 + cb[pi]];
                    float v1 = Sh[ER + FB +  420 + cb[pi]];
                    float v2 = Sh[ER + FB +  840 + cb[pi]];
                    float v3 = Sh[ER + FB + 1260 + cb[pi]];
                    if (!okb[pi]) { v0 = v1 = v2 = v3 = 0.0f; }
                    bLo[pi] = make_uint2(pk2(v0, v1), pk2(v2, v3));
                } else bLo[pi] = make_uint2(0u, 0u);
            }
            #pragma unroll
            for (int a = 0; a < 7; ++a) {
                const int r = p0 - 5 + a;
                if (r >= 0 && r <= 25) {
                    const int col = 16 * r + l15;
                    const float v0 = Sh[EL + FB +    0 + col];
                    const float v1 = Sh[EL + FB +  420 + col];
                    const float v2 = Sh[EL + FB +  840 + col];
                    const float v3 = Sh[EL + FB + 1260 + col];
                    aLo[a] = make_uint2(pk2(v0, v1), pk2(v2, v3));
                } else aLo[a] = make_uint2(0u, 0u);
            }
            full_barrier();   // odd staged; even reads done

            // ======== sub-phase B: stage chunk 2m+2 (or seam: slab1 ch0) -> even;
            //          HI halves from odd + MFMA ========
            if (m < 7) {
                const size_t co = (size_t)(2 * m + 2) * 16 * HW;
                gl16(Ls + co, dEL); gl16(Rs + co, dER);
                if (l < 40) { gl16(Ls + co + 256, dEL + 256); gl16(Rs + co + 256, dER + 256); }
            } else if (s == 0) {
                const float* Ln = gLw + WSZ;   // slab1 chunk0
                const float* Rn = gRw + WSZ;
                gl16(Ln, dEL); gl16(Rn, dER);
                if (l < 40) { gl16(Ln + 256, dEL + 256); gl16(Rn + 256, dER + 256); }
            }
            bf16x8 bF[2];
            #pragma unroll
            for (int pi = 0; pi < 2; ++pi) {
                if (pi == 0 || hasP1) {
                    float v0 = Sh[ORR + FB +    0 + cb[pi]];
                    float v1 = Sh[ORR + FB +  420 + cb[pi]];
                    float v2 = Sh[ORR + FB +  840 + cb[pi]];
                    float v3 = Sh[ORR + FB + 1260 + cb[pi]];
                    if (!okb[pi]) { v0 = v1 = v2 = v3 = 0.0f; }
                    U8 x; x.u[0] = bLo[pi].x; x.u[1] = bLo[pi].y;
                    x.u[2] = pk2(v0, v1); x.u[3] = pk2(v2, v3);
                    bF[pi] = x.v;
                } else {
                    U8 z; z.u[0] = z.u[1] = z.u[2] = z.u[3] = 0u;
                    bF[pi] = z.v;
                }
            }
            #pragma unroll
            for (int a = 0; a < 7; ++a) {
                const int r = p0 - 5 + a;
                if (r >= 0 && r <= 25) {
                    const int col = 16 * r + l15;
                    const float v0 = Sh[OL + FB +    0 + col];
                    const float v1 = Sh[OL + FB +  420 + col];
                    const float v2 = Sh[OL + FB +  840 + col];
                    const float v3 = Sh[OL + FB + 1260 + col];
                    U8 x; x.u[0] = aLo[a].x; x.u[1] = aLo[a].y;
                    x.u[2] = pk2(v0, v1); x.u[3] = pk2(v2, v3);
                    if (a < 6)
                        acc0[a] = __builtin_amdgcn_mfma_f32_16x16x32_bf16(x.v, bF[0], acc0[a], 0, 0, 0);
                    if (hasP1 && a >= 1)
                        acc1[a - 1] = __builtin_amdgcn_mfma_f32_16x16x32_bf16(x.v, bF[1], acc1[a - 1], 0, 0, 0);
                }
            }
            full_barrier();   // even staged; odd reads done
        }

        // ---- epilogue slab s: scratch = odd region (free), 3 d-groups of 27 ----
        float* outp = out + (size_t)b * ND * HW + (size_t)(2 * hp + s) * WSZ;
        float* Shf = &Sh[OL];

        for (int g = 0; g < 3; ++g) {
            const int d0 = 27 * g;
            #pragma unroll
            for (int pi = 0; pi < 2; ++pi) {
                if (pi == 0 || hasP1) {
                    #pragma unroll
                    for (int k = 0; k < 6; ++k) {
                        const int r = p0 - 5 + pi + k;
                        if (r >= 0 && r <= 25) {
                            const int j = 5 - k;
                            const f32x4 av = pi ? acc1[k] : acc0[k];
                            #pragma unroll
                            for (int rr = 0; rr < 4; ++rr) {
                                const int mm = 4 * l4 + rr;
                                const int d  = 16 * j + l15 - mm;
                                if ((unsigned)(d - d0) < 27u)
                                    Shf[(d - d0) * ESTR + 16 * r + mm] = av[rr] * scale;
                            }
                        }
                    }
                }
            }
            lds_barrier();
            #pragma unroll
            for (int i = 0; i < 3; ++i) {
                const int idx = i * 1024 + t;
                if (idx < 27 * 104) {
                    const int d = idx / 104;
                    const int q = idx - 104 * d;
                    *(f32x4*)(outp + (size_t)(d0 + d) * HW + 4 * q) = *(const f32x4*)&Shf[d * ESTR + 4 * q];
                }
            }
            lds_barrier();   // store reads done before next scatter / next subA stage-to-odd
        }

        if (s == 0) {
            #pragma unroll
            for (int k = 0; k < 6; ++k) { acc0[k] = (f32x4)0.0f; acc1[k] = (f32x4)0.0f; }
        }
    }
}

extern "C" void kernel_launch(void* const* d_in, const int* in_sizes, int n_in,
                              void* d_out, int out_size, void* d_ws, size_t ws_size,
                              hipStream_t stream) {
    const float* left  = (const float*)d_in[0];
    const float* right = (const float*)d_in[1];
    float* out = (float*)d_out;
    (void)in_sizes; (void)n_in; (void)out_size; (void)d_ws; (void)ws_size;
    corr_mfma_kernel<<<dim3(256), dim3(1024), 0, stream>>>(left, right, out);
}